// Round 7
// baseline (181.085 us; speedup 1.0000x reference)
//
#include <hip/hip_runtime.h>
#include <hip/hip_bf16.h>

#define NN 32
#define CIN 64
#define TTOT 300
#define VV 25
#define PP 3
#define COUT 128
#define KTOT 192     // P*CIN
#define TTILE 5
#define NTILES 60
#define CNT 240000.0f
#define NCOLS 240000 // N*T*V
#define NBLK 1920    // aggstats grid = NN*NTILES

#define XSTR 40      // X/At w-stride in shorts
#define ZSTR 72      // fallback-path Z2 c-stride
#define ZROWS 128

// ws float offsets (front region)
#define WS_STATS 0    // 256 f32 (fallback path only)
#define WS_SCALE 256  // 128 f32
#define WS_SHIFT 384  // 128 f32
#define WS_BSUM  512  // 128 f32
#define WS_W2    640  // bf16[128*192]; W2[o][p*64+c]
#define WS_PART  32768            // f32[1920][256] partials (~2 MB)
#define ZT_BYTE_OFF (4u << 20)    // Zt bf16[240000][192] at +4MB
#define WS_NEEDED (ZT_BYTE_OFF + (size_t)NCOLS * KTOT * 2)

typedef float f32x4 __attribute__((ext_vector_type(4)));
typedef short s16x8 __attribute__((ext_vector_type(8)));

__device__ __forceinline__ short f2bf(float f) {
    unsigned u = __float_as_uint(f);
    u += 0x7fff + ((u >> 16) & 1);          // RNE
    return (short)(u >> 16);
}

__global__ __launch_bounds__(256) void prep_kernel(const float* __restrict__ W,
                                                   const float* __restrict__ b,
                                                   float* __restrict__ ws) {
    int tid = blockIdx.x * blockDim.x + threadIdx.x;
    if (tid < 256) ws[WS_STATS + tid] = 0.0f;               // fallback path zeroing
    if (tid >= 256 && tid < 384) {
        int o = tid - 256;
        ws[WS_BSUM + o] = b[o] + b[COUT + o] + b[2 * COUT + o];
    }
    if (tid < COUT * KTOT) {                                 // W2[o][k], k = p*64+c
        int o = tid / KTOT, k = tid % KTOT;
        int p = k / 64, c = k % 64;
        ((short*)(ws + WS_W2))[tid] = f2bf(W[(p * COUT + o) * CIN + c]);
    }
}

// ---------------- fast path ----------------

// aggstats: x -> Z (global Zt + local swizzled LDS) -> conv -> partial stats.
// LDS: 48KB Z2 tile unioned over X/At staging (dead after reg-prefetch) + sstat.
__global__ __launch_bounds__(512, 4) void aggstats_kernel(const float* __restrict__ x,
                                                          const float* __restrict__ A,
                                                          short* __restrict__ Zt,
                                                          float* __restrict__ ws) {
    __shared__ __align__(16) short SM[128 * KTOT];   // 49152 B; front 33280 B = Xs|Ats
    __shared__ float sstat[256];
    short* Xs  = SM;                  // [5][64][XSTR] = 12800 shorts
    short* Ats = SM + 12800;          // [3][32][XSTR] = 3840 shorts

    const int tid  = threadIdx.x;
    const int lane = tid & 63;
    const int wave = tid >> 6;
    const int n  = blockIdx.x / NTILES;
    const int t0 = (blockIdx.x % NTILES) * TTILE;
    const int lg = lane >> 4;
    const int li = lane & 15;

    // ---- phase A: stage Xs/Ats; zero Z2 pad rows (bytes 48000..49152); sstat ----
    {
        const float* xb = x + (size_t)n * (CIN * TTOT * VV) + (size_t)t0 * VV;
        #pragma unroll
        for (int it = 0; it < 20; ++it) {                   // 20*512 = 64*5*32
            int i = tid + it * 512;
            int c = i / 160;
            int r2 = i - c * 160;
            int t = r2 >> 5, w = r2 & 31;
            float val = (w < VV) ? xb[c * (TTOT * VV) + t * VV + w] : 0.0f;
            Xs[(t * 64 + c) * XSTR + w] = f2bf(val);
        }
        #pragma unroll
        for (int it = 0; it < 8; ++it) {
            int i = tid + it * 512;
            if (i < PP * 32 * XSTR) {
                int p = i / (32 * XSTR);
                int r = i - p * (32 * XSTR);
                int v = r / XSTR, w = r - v * XSTR;
                Ats[i] = (v < VV && w < VV) ? f2bf(A[p * (VV * VV) + w * VV + v])
                                            : (short)0;
            }
        }
        if (tid < 288) ((int*)(SM + 125 * KTOT))[tid] = 0;   // pad cols 125..127
        if (tid < 256) sstat[tid] = 0.0f;
    }
    __syncthreads();

    // ---- phase B: register-prefetch fragments (Xs/Ats dead afterwards) ----
    const int acf = wave >> 1;         // agg c-frag 0..3
    const int avf = wave & 1;          // agg v-frag 0..1
    const int vv  = avf * 16 + li;
    s16x8 xa[TTILE];
    #pragma unroll
    for (int t = 0; t < TTILE; ++t)
        xa[t] = *(const s16x8*)(&Xs[(t * 64 + acf * 16 + li) * XSTR + lg * 8]);
    s16x8 af[PP];
    #pragma unroll
    for (int p = 0; p < PP; ++p)
        af[p] = *(const s16x8*)(&Ats[(p * 32 + avf * 16 + li) * XSTR + lg * 8]);
    __syncthreads();   // all waves done reading Xs/Ats before Z2 overwrites

    // ---- phase C: agg MFMAs -> write Zt (global) + Z2 (swizzled LDS) ----
    const bool vok = (vv < VV);
    const size_t colbase = (size_t)n * 7500 + (size_t)t0 * VV + vv;
    const int kbase = acf * 16 + lg * 4;            // k within a p-group
    #pragma unroll
    for (int t = 0; t < TTILE; ++t) {
        #pragma unroll
        for (int p = 0; p < PP; ++p) {
            f32x4 z = (f32x4){0.f, 0.f, 0.f, 0.f};
            f32x4 d = __builtin_amdgcn_mfma_f32_16x16x32_bf16(xa[t], af[p], z, 0, 0, 0);
            if (vok) {
                ushort4 pk;
                pk.x = (unsigned short)f2bf(d[0]);
                pk.y = (unsigned short)f2bf(d[1]);
                pk.z = (unsigned short)f2bf(d[2]);
                pk.w = (unsigned short)f2bf(d[3]);
                *(ushort4*)(&Zt[(colbase + (size_t)t * VV) * KTOT + p * 64 + kbase]) = pk;
                int lcol = t * VV + vv;
                int byte = (lcol * 384 + (p * 64 + kbase) * 2) ^ ((lcol & 7) << 4);
                *(ushort4*)((char*)SM + byte) = pk;
            }
        }
    }
    __syncthreads();   // Z2 complete

    // ---- phase D: conv for this block's 128 cols (125 real + 3 zero pads) ----
    const short* w2 = (const short*)(ws + WS_W2);
    const int ow = wave >> 1;          // o0 = ow*32
    const int ch = wave & 1;           // col half
    const int o0 = ow * 32;

    f32x4 acc[2][4];
    #pragma unroll
    for (int mf = 0; mf < 2; ++mf)
        #pragma unroll
        for (int cf = 0; cf < 4; ++cf)
            acc[mf][cf] = (f32x4){0.f, 0.f, 0.f, 0.f};

    #pragma unroll
    for (int ks = 0; ks < 6; ++ks) {
        s16x8 wf0 = *(const s16x8*)(w2 + (o0 + li) * KTOT + ks * 32 + lg * 8);
        s16x8 wf1 = *(const s16x8*)(w2 + (o0 + 16 + li) * KTOT + ks * 32 + lg * 8);
        #pragma unroll
        for (int cf = 0; cf < 4; ++cf) {
            int lcol = ch * 64 + cf * 16 + li;
            int byte = (lcol * 384 + ks * 64 + lg * 16) ^ ((lcol & 7) << 4);
            s16x8 zf = *(const s16x8*)((const char*)SM + byte);
            acc[0][cf] = __builtin_amdgcn_mfma_f32_16x16x32_bf16(wf0, zf, acc[0][cf], 0, 0, 0);
            acc[1][cf] = __builtin_amdgcn_mfma_f32_16x16x32_bf16(wf1, zf, acc[1][cf], 0, 0, 0);
        }
    }

    // ---- phase E: partial stats (exclude pad cols), no y write, no global atomics ----
    const float* bsum = ws + WS_BSUM;
    #pragma unroll
    for (int mf = 0; mf < 2; ++mf) {
        #pragma unroll
        for (int r = 0; r < 4; ++r) {
            float bo = bsum[o0 + mf * 16 + lg * 4 + r];
            float s = 0.f, sq = 0.f;
            #pragma unroll
            for (int cf = 0; cf < 4; ++cf) {
                int lcol = ch * 64 + cf * 16 + li;
                float val = acc[mf][cf][r] + bo;
                if (lcol < TTILE * VV) { s += val; sq += val * val; }
            }
            #pragma unroll
            for (int m = 1; m < 16; m <<= 1) {
                s  += __shfl_xor(s, m, 64);
                sq += __shfl_xor(sq, m, 64);
            }
            if (li == 0) {
                int o = o0 + mf * 16 + lg * 4 + r;
                atomicAdd(&sstat[o], s);          // LDS atomic (cheap)
                atomicAdd(&sstat[128 + o], sq);
            }
        }
    }
    __syncthreads();
    if (tid < 256) ws[WS_PART + blockIdx.x * 256 + tid] = sstat[tid];
}

__global__ void finalize_partials(const float* __restrict__ gamma,
                                  const float* __restrict__ beta,
                                  float* ws) {
    // 128 blocks x 128 threads: block = o; wave0 sums, wave1 sumsq
    __shared__ float red[2];
    const int o = blockIdx.x;
    const int wave = threadIdx.x >> 6;
    const int lane = threadIdx.x & 63;
    float acc = 0.f;
    #pragma unroll
    for (int it = 0; it < NBLK / 64; ++it) {
        int blk = lane + it * 64;
        acc += ws[WS_PART + blk * 256 + wave * 128 + o];
    }
    #pragma unroll
    for (int m = 1; m < 64; m <<= 1) acc += __shfl_xor(acc, m, 64);
    if (lane == 0) red[wave] = acc;
    __syncthreads();
    if (threadIdx.x == 0) {
        float mean = red[0] * (1.0f / CNT);
        float ex2  = red[1] * (1.0f / CNT);
        float var  = ex2 - mean * mean;
        float rstd = rsqrtf(var + 1e-5f);
        float sc = gamma[o] * rstd;
        ws[WS_SCALE + o] = sc;
        ws[WS_SHIFT + o] = beta[o] - mean * sc;
    }
}

// conv_apply: Zt -> y final (BN+ReLU fused). No LDS, no barriers: Z fragments
// read straight from global (each Z element consumed exactly once; 4 lg-lanes
// cover each 64B line). grid 1875.
__global__ __launch_bounds__(512, 4) void conv_apply(const short* __restrict__ Zt,
                                                     float* __restrict__ y,
                                                     const float* __restrict__ ws) {
    const int tid  = threadIdx.x;
    const int lane = tid & 63;
    const int wave = tid >> 6;
    const int lg = lane >> 4;
    const int li = lane & 15;
    const int c0 = blockIdx.x * 128;
    const int ow = wave >> 1;
    const int ch = wave & 1;
    const int o0 = ow * 32;

    const short* w2 = (const short*)(ws + WS_W2);
    s16x8 wf[2][6];
    #pragma unroll
    for (int mf = 0; mf < 2; ++mf)
        #pragma unroll
        for (int ks = 0; ks < 6; ++ks)
            wf[mf][ks] = *(const s16x8*)(w2 + (o0 + mf * 16 + li) * KTOT
                                            + ks * 32 + lg * 8);

    f32x4 acc[2][4];
    #pragma unroll
    for (int mf = 0; mf < 2; ++mf)
        #pragma unroll
        for (int cf = 0; cf < 4; ++cf)
            acc[mf][cf] = (f32x4){0.f, 0.f, 0.f, 0.f};

    #pragma unroll
    for (int cf = 0; cf < 4; ++cf) {
        const short* zp = Zt + (size_t)(c0 + ch * 64 + cf * 16 + li) * KTOT + lg * 8;
        s16x8 zf0 = *(const s16x8*)(zp);
        s16x8 zf1 = *(const s16x8*)(zp + 32);
        s16x8 zf2 = *(const s16x8*)(zp + 64);
        s16x8 zf3 = *(const s16x8*)(zp + 96);
        s16x8 zf4 = *(const s16x8*)(zp + 128);
        s16x8 zf5 = *(const s16x8*)(zp + 160);
        acc[0][cf] = __builtin_amdgcn_mfma_f32_16x16x32_bf16(wf[0][0], zf0, acc[0][cf], 0, 0, 0);
        acc[1][cf] = __builtin_amdgcn_mfma_f32_16x16x32_bf16(wf[1][0], zf0, acc[1][cf], 0, 0, 0);
        acc[0][cf] = __builtin_amdgcn_mfma_f32_16x16x32_bf16(wf[0][1], zf1, acc[0][cf], 0, 0, 0);
        acc[1][cf] = __builtin_amdgcn_mfma_f32_16x16x32_bf16(wf[1][1], zf1, acc[1][cf], 0, 0, 0);
        acc[0][cf] = __builtin_amdgcn_mfma_f32_16x16x32_bf16(wf[0][2], zf2, acc[0][cf], 0, 0, 0);
        acc[1][cf] = __builtin_amdgcn_mfma_f32_16x16x32_bf16(wf[1][2], zf2, acc[1][cf], 0, 0, 0);
        acc[0][cf] = __builtin_amdgcn_mfma_f32_16x16x32_bf16(wf[0][3], zf3, acc[0][cf], 0, 0, 0);
        acc[1][cf] = __builtin_amdgcn_mfma_f32_16x16x32_bf16(wf[1][3], zf3, acc[1][cf], 0, 0, 0);
        acc[0][cf] = __builtin_amdgcn_mfma_f32_16x16x32_bf16(wf[0][4], zf4, acc[0][cf], 0, 0, 0);
        acc[1][cf] = __builtin_amdgcn_mfma_f32_16x16x32_bf16(wf[1][4], zf4, acc[1][cf], 0, 0, 0);
        acc[0][cf] = __builtin_amdgcn_mfma_f32_16x16x32_bf16(wf[0][5], zf5, acc[0][cf], 0, 0, 0);
        acc[1][cf] = __builtin_amdgcn_mfma_f32_16x16x32_bf16(wf[1][5], zf5, acc[1][cf], 0, 0, 0);
    }

    const float* bsum = ws + WS_BSUM;
    const float* scale = ws + WS_SCALE;
    const float* shift = ws + WS_SHIFT;
    #pragma unroll
    for (int mf = 0; mf < 2; ++mf) {
        float4 scv = *(const float4*)(scale + o0 + mf * 16 + lg * 4);
        float4 shv = *(const float4*)(shift + o0 + mf * 16 + lg * 4);
        float4 bov = *(const float4*)(bsum  + o0 + mf * 16 + lg * 4);
        float scr[4] = {scv.x, scv.y, scv.z, scv.w};
        float shr[4] = {shv.x, shv.y, shv.z, shv.w};
        float bor[4] = {bov.x, bov.y, bov.z, bov.w};
        #pragma unroll
        for (int r = 0; r < 4; ++r) {
            int o = o0 + mf * 16 + lg * 4 + r;
            #pragma unroll
            for (int cf = 0; cf < 4; ++cf) {
                int col = c0 + ch * 64 + cf * 16 + li;
                float val = acc[mf][cf][r] + bor[r];
                val = fmaxf(val * scr[r] + shr[r], 0.0f);
                int n = col / 7500;
                int inner = col - n * 7500;
                y[(size_t)(n * COUT + o) * 7500 + inner] = val;
            }
        }
    }
}

// ---------------- fused fallback (R4) + tail, used only if ws too small ----------------
__global__ __launch_bounds__(512, 4) void sgcn_main(const float* __restrict__ x,
                                                    const float* __restrict__ A,
                                                    float* __restrict__ y,
                                                    float* ws) {
    __shared__ __align__(16) short Xs[TTILE * 64 * XSTR];
    __shared__ __align__(16) short Ats[PP * 32 * XSTR];
    __shared__ __align__(16) short Z2s[ZROWS * ZSTR];
    __shared__ float sstat[256];

    const int tid  = threadIdx.x;
    const int lane = tid & 63;
    const int wave = tid >> 6;
    const int n  = blockIdx.x / NTILES;
    const int t0 = (blockIdx.x % NTILES) * TTILE;
    const int lg = lane >> 4;
    const int li = lane & 15;

    {
        const float* xb = x + (size_t)n * (CIN * TTOT * VV) + (size_t)t0 * VV;
        #pragma unroll
        for (int it = 0; it < 20; ++it) {
            int i = tid + it * 512;
            int c = i / 160;
            int r2 = i - c * 160;
            int t = r2 >> 5, w = r2 & 31;
            float val = (w < VV) ? xb[c * (TTOT * VV) + t * VV + w] : 0.0f;
            Xs[(t * 64 + c) * XSTR + w] = f2bf(val);
        }
        #pragma unroll
        for (int it = 0; it < 8; ++it) {
            int i = tid + it * 512;
            if (i < PP * 32 * XSTR) {
                int p = i / (32 * XSTR);
                int r = i - p * (32 * XSTR);
                int v = r / XSTR, w = r - v * XSTR;
                Ats[i] = (v < VV && w < VV) ? f2bf(A[p * (VV * VV) + w * VV + v])
                                            : (short)0;
            }
        }
        if (tid < 108) ((int*)(Z2s + 125 * ZSTR))[tid] = 0;
        if (tid < 256) sstat[tid] = 0.0f;
    }
    __syncthreads();

    const int ow = wave >> 1;
    const int cw = wave & 1;
    const int o0 = ow * 32;
    const short* w2 = (const short*)(ws + WS_W2);

    f32x4 acc[2][4];
    #pragma unroll
    for (int mf = 0; mf < 2; ++mf)
        #pragma unroll
        for (int cf = 0; cf < 4; ++cf)
            acc[mf][cf] = (f32x4){0.f, 0.f, 0.f, 0.f};

    for (int p = 0; p < PP; ++p) {
        s16x8 wfl[2][2];
        #pragma unroll
        for (int mf = 0; mf < 2; ++mf)
            #pragma unroll
            for (int ks = 0; ks < 2; ++ks)
                wfl[mf][ks] = *(const s16x8*)(w2 + (o0 + mf * 16 + li) * KTOT
                                                 + p * 64 + ks * 32 + lg * 8);
        #pragma unroll
        for (int q = 0; q < 5; ++q) {
            int f = wave * 5 + q;
            int t = f >> 3, rem = f & 7;
            int vf = rem >> 2, cfr = rem & 3;
            s16x8 af = *(const s16x8*)(&Ats[(p * 32 + vf * 16 + li) * XSTR + lg * 8]);
            s16x8 bf = *(const s16x8*)(&Xs[(t * 64 + cfr * 16 + li) * XSTR + lg * 8]);
            f32x4 z = (f32x4){0.f, 0.f, 0.f, 0.f};
            f32x4 d = __builtin_amdgcn_mfma_f32_16x16x32_bf16(af, bf, z, 0, 0, 0);
            int m0 = vf * 16 + lg * 4;
            int ccol = cfr * 16 + li;
            #pragma unroll
            for (int r = 0; r < 4; ++r) {
                int m = m0 + r;
                if (m < VV) Z2s[(t * VV + m) * ZSTR + ccol] = f2bf(d[r]);
            }
        }
        __syncthreads();
        #pragma unroll
        for (int cf = 0; cf < 4; ++cf) {
            int col0 = cw * 64 + cf * 16;
            #pragma unroll
            for (int ks = 0; ks < 2; ++ks) {
                s16x8 zf = *(const s16x8*)(&Z2s[(col0 + li) * ZSTR + ks * 32 + lg * 8]);
                #pragma unroll
                for (int mf = 0; mf < 2; ++mf)
                    acc[mf][cf] = __builtin_amdgcn_mfma_f32_16x16x32_bf16(
                        wfl[mf][ks], zf, acc[mf][cf], 0, 0, 0);
            }
        }
        __syncthreads();
    }

    const float* bsum = ws + WS_BSUM;
    #pragma unroll
    for (int mf = 0; mf < 2; ++mf) {
        #pragma unroll
        for (int r = 0; r < 4; ++r) {
            int o = o0 + mf * 16 + lg * 4 + r;
            float bo = bsum[o];
            float s = 0.f, sq = 0.f;
            #pragma unroll
            for (int cf = 0; cf < 4; ++cf) {
                int col = cw * 64 + cf * 16 + li;
                float val = acc[mf][cf][r] + bo;
                if (col < TTILE * VV) {
                    y[(size_t)(n * COUT + o) * (TTOT * VV) + t0 * VV + col] = val;
                    s += val; sq += val * val;
                }
            }
            #pragma unroll
            for (int m = 1; m < 16; m <<= 1) {
                s  += __shfl_xor(s, m, 64);
                sq += __shfl_xor(sq, m, 64);
            }
            if (li == 0) {
                atomicAdd(&sstat[o], s);
                atomicAdd(&sstat[128 + o], sq);
            }
        }
    }
    __syncthreads();
    if (tid < 256) atomicAdd(&ws[WS_STATS + tid], sstat[tid]);
}

__global__ void finalize_kernel(const float* __restrict__ gamma,
                                const float* __restrict__ beta,
                                float* ws) {
    int o = threadIdx.x;
    float mean = ws[WS_STATS + o] * (1.0f / CNT);
    float ex2  = ws[WS_STATS + 128 + o] * (1.0f / CNT);
    float var  = ex2 - mean * mean;
    float rstd = rsqrtf(var + 1e-5f);
    float sc = gamma[o] * rstd;
    ws[WS_SCALE + o] = sc;
    ws[WS_SHIFT + o] = beta[o] - mean * sc;
}

__global__ __launch_bounds__(256) void norm_relu_kernel(float* __restrict__ y,
                                                        const float* __restrict__ ws) {
    const int total8 = (NN * COUT * TTOT * VV) / 8;
    const float* scale = ws + WS_SCALE;
    const float* shift = ws + WS_SHIFT;
    for (int i = blockIdx.x * blockDim.x + threadIdx.x; i < total8;
         i += gridDim.x * blockDim.x) {
        size_t base = (size_t)i * 8;
        int row0 = (int)(base / 7500);
        int row1 = (int)((base + 7) / 7500);
        int o0 = row0 & 127, o1 = row1 & 127;
        float s0 = scale[o0], h0 = shift[o0];
        float s1 = scale[o1], h1 = shift[o1];
        size_t bnd = (size_t)(row0 + 1) * 7500;
        float4 a = *(const float4*)(y + base);
        float4 b = *(const float4*)(y + base + 4);
        float vals[8] = {a.x, a.y, a.z, a.w, b.x, b.y, b.z, b.w};
        #pragma unroll
        for (int e = 0; e < 8; ++e) {
            bool first = (base + (size_t)e) < bnd;
            float sv = first ? s0 : s1;
            float hv = first ? h0 : h1;
            vals[e] = fmaxf(vals[e] * sv + hv, 0.0f);
        }
        a = make_float4(vals[0], vals[1], vals[2], vals[3]);
        b = make_float4(vals[4], vals[5], vals[6], vals[7]);
        *(float4*)(y + base) = a;
        *(float4*)(y + base + 4) = b;
    }
}

extern "C" void kernel_launch(void* const* d_in, const int* in_sizes, int n_in,
                              void* d_out, int out_size, void* d_ws, size_t ws_size,
                              hipStream_t stream) {
    const float* x     = (const float*)d_in[0];
    const float* A     = (const float*)d_in[1];
    const float* W     = (const float*)d_in[2];
    const float* b     = (const float*)d_in[3];
    const float* gamma = (const float*)d_in[4];
    const float* beta  = (const float*)d_in[5];
    float* y  = (float*)d_out;
    float* ws = (float*)d_ws;

    prep_kernel<<<96, 256, 0, stream>>>(W, b, ws);
    if (ws_size >= WS_NEEDED) {
        short* Zt = (short*)((char*)d_ws + ZT_BYTE_OFF);
        aggstats_kernel<<<NBLK, 512, 0, stream>>>(x, A, Zt, ws);
        finalize_partials<<<COUT, 128, 0, stream>>>(gamma, beta, ws);
        conv_apply<<<NCOLS / 128, 512, 0, stream>>>(Zt, y, ws);
    } else {
        sgcn_main<<<NN * NTILES, 512, 0, stream>>>(x, A, y, ws);
        finalize_kernel<<<1, 128, 0, stream>>>(gamma, beta, ws);
        norm_relu_kernel<<<2048, 256, 0, stream>>>(y, ws);
    }
}